// Round 1
// baseline (681.572 us; speedup 1.0000x reference)
//
#include <hip/hip_runtime.h>

// Prompts kernel: out[row, k] = softmax_k( exp(logit_scale) * dot(x[row,:], tf[k,:]/||tf[k]||) )
// B*N = 262144 rows, D = 512, K = 2.  Memory-bound: stream 512 MiB of x.
//
// Layout: one wave (64 lanes) per row. Lane i holds x/weight elements
// [4i, 4i+4) and [256+4i, 256+4i+4) as float4 -> coalesced 1 KiB per
// global_load_dwordx4 across the wave.

#define D_DIM 512

__device__ __forceinline__ float dot4(float4 a, float4 b) {
    return a.x * b.x + a.y * b.y + a.z * b.z + a.w * b.w;
}

__device__ __forceinline__ float wave_reduce_sum(float v) {
#pragma unroll
    for (int off = 32; off >= 1; off >>= 1)
        v += __shfl_xor(v, off, 64);
    return v;  // all 64 lanes hold the sum after the butterfly
}

__global__ __launch_bounds__(256, 8) void prompts_kernel(
    const float* __restrict__ x,
    const float* __restrict__ tf,
    const float* __restrict__ logit_scale,
    float* __restrict__ out,
    int nrows)
{
    const int lane            = threadIdx.x & 63;
    const int wave_in_block   = threadIdx.x >> 6;
    const int waves_per_block = blockDim.x >> 6;
    const int gwave  = blockIdx.x * waves_per_block + wave_in_block;
    const int nwaves = gridDim.x * waves_per_block;

    // ---- Per-wave weight setup (tiny; tf is 4 KiB, L2-resident) ----
    const float4* tf4 = (const float4*)tf;
    float4 w0a = tf4[lane];        // tf row 0, elements [4i, 4i+4)
    float4 w0b = tf4[64 + lane];   // tf row 0, elements [256+4i, ...)
    float4 w1a = tf4[128 + lane];  // tf row 1
    float4 w1b = tf4[192 + lane];

    float ss0 = wave_reduce_sum(dot4(w0a, w0a) + dot4(w0b, w0b));
    float ss1 = wave_reduce_sum(dot4(w1a, w1a) + dot4(w1b, w1b));

    const float scale = expf(logit_scale[0]);   // = 100.0
    const float inv0  = scale / sqrtf(ss0);
    const float inv1  = scale / sqrtf(ss1);

    w0a.x *= inv0; w0a.y *= inv0; w0a.z *= inv0; w0a.w *= inv0;
    w0b.x *= inv0; w0b.y *= inv0; w0b.z *= inv0; w0b.w *= inv0;
    w1a.x *= inv1; w1a.y *= inv1; w1a.z *= inv1; w1a.w *= inv1;
    w1b.x *= inv1; w1b.y *= inv1; w1b.z *= inv1; w1b.w *= inv1;

    // ---- Grid-stride over rows, one row per wave per iteration ----
    const float4* x4   = (const float4*)x;
    float2*       out2 = (float2*)out;

    for (int row = gwave; row < nrows; row += nwaves) {
        const size_t base = (size_t)row * (D_DIM / 4);
        float4 xa = x4[base + lane];
        float4 xb = x4[base + 64 + lane];

        float d0 = dot4(xa, w0a) + dot4(xb, w0b);
        float d1 = dot4(xa, w1a) + dot4(xb, w1b);

#pragma unroll
        for (int off = 32; off >= 1; off >>= 1) {
            d0 += __shfl_xor(d0, off, 64);
            d1 += __shfl_xor(d1, off, 64);
        }

        if (lane == 0) {
            // softmax over 2: p0 = 1/(1+e^(l1-l0)); overflow-safe (inf -> 0)
            float e0 = expf(d1 - d0);
            float e1 = expf(d0 - d1);
            float2 p;
            p.x = 1.0f / (1.0f + e0);
            p.y = 1.0f / (1.0f + e1);
            out2[row] = p;
        }
    }
}

extern "C" void kernel_launch(void* const* d_in, const int* in_sizes, int n_in,
                              void* d_out, int out_size, void* d_ws, size_t ws_size,
                              hipStream_t stream) {
    const float* x  = (const float*)d_in[0];
    const float* tf = (const float*)d_in[1];
    const float* ls = (const float*)d_in[2];
    float* out = (float*)d_out;

    const int nrows = in_sizes[0] / D_DIM;  // 262144

    // 2048 blocks x 256 thr = 8192 waves (8 blocks/CU target), 32 rows/wave
    prompts_kernel<<<2048, 256, 0, stream>>>(x, tf, ls, out, nrows);
}

// Round 2
// 678.498 us; speedup vs baseline: 1.0045x; 1.0045x over previous
//
#include <hip/hip_runtime.h>

// Prompts: out[row,k] = softmax_k( 100 * dot(x[row,:], tf[k,:]/||tf[k]||) )
// rows = 262144, D = 512, K = 2. Memory-bound: stream 512 MiB of x -> ~86 us floor.
//
// One wave per 4 rows per iteration:
//   - 8 independent global_load_dwordx4 (4 rows x 2 half-rows), coalesced 1 KiB each
//   - 8 independent 6-step butterfly reductions (ILP across them)
//   - lanes 0..3 store 4 consecutive float2 -> 32 B contiguous
// __launch_bounds__(256,4): VGPR cap 128 (tally ~95) -> no scratch spills.

#define D_DIM 512

__device__ __forceinline__ float dot4(float4 a, float4 b) {
    return a.x * b.x + a.y * b.y + a.z * b.z + a.w * b.w;
}

__global__ __launch_bounds__(256, 4) void prompts_kernel(
    const float* __restrict__ x,
    const float* __restrict__ tf,
    const float* __restrict__ logit_scale,
    float* __restrict__ out,
    int nrows)
{
    const int lane          = threadIdx.x & 63;
    const int wave_in_block = threadIdx.x >> 6;
    const int gwave  = blockIdx.x * (blockDim.x >> 6) + wave_in_block;
    const int nwaves = gridDim.x * (blockDim.x >> 6);

    // ---- Per-wave weight setup (tf is 4 KiB, L2-resident) ----
    const float4* tf4 = (const float4*)tf;
    float4 w0a = tf4[lane];        // tf row 0, floats [4i, 4i+4)
    float4 w0b = tf4[64 + lane];   // tf row 0, floats [256+4i, ...)
    float4 w1a = tf4[128 + lane];  // tf row 1
    float4 w1b = tf4[192 + lane];

    float ss0 = dot4(w0a, w0a) + dot4(w0b, w0b);
    float ss1 = dot4(w1a, w1a) + dot4(w1b, w1b);
#pragma unroll
    for (int off = 32; off >= 1; off >>= 1) {
        ss0 += __shfl_xor(ss0, off, 64);
        ss1 += __shfl_xor(ss1, off, 64);
    }

    const float scale = expf(logit_scale[0]);   // = 100.0
    const float inv0  = scale / sqrtf(ss0);
    const float inv1  = scale / sqrtf(ss1);

    w0a.x *= inv0; w0a.y *= inv0; w0a.z *= inv0; w0a.w *= inv0;
    w0b.x *= inv0; w0b.y *= inv0; w0b.z *= inv0; w0b.w *= inv0;
    w1a.x *= inv1; w1a.y *= inv1; w1a.z *= inv1; w1a.w *= inv1;
    w1b.x *= inv1; w1b.y *= inv1; w1b.z *= inv1; w1b.w *= inv1;

    // ---- Grid-stride, 4 rows per wave-iteration ----
    const float4* x4   = (const float4*)x;
    float2*       out2 = (float2*)out;

    for (int row0 = gwave * 4; row0 < nrows; row0 += nwaves * 4) {
        const float4* p = x4 + (size_t)row0 * (D_DIM / 4);

        // 8 independent 16B loads: maximal MLP, all issued before any use
        float4 xa0 = p[lane      ], xb0 = p[lane +  64];
        float4 xa1 = p[lane + 128], xb1 = p[lane + 192];
        float4 xa2 = p[lane + 256], xb2 = p[lane + 320];
        float4 xa3 = p[lane + 384], xb3 = p[lane + 448];

        float s00 = dot4(xa0, w0a) + dot4(xb0, w0b);
        float s10 = dot4(xa0, w1a) + dot4(xb0, w1b);
        float s01 = dot4(xa1, w0a) + dot4(xb1, w0b);
        float s11 = dot4(xa1, w1a) + dot4(xb1, w1b);
        float s02 = dot4(xa2, w0a) + dot4(xb2, w0b);
        float s12 = dot4(xa2, w1a) + dot4(xb2, w1b);
        float s03 = dot4(xa3, w0a) + dot4(xb3, w0b);
        float s13 = dot4(xa3, w1a) + dot4(xb3, w1b);

        // 8 independent butterflies -> ILP hides ds_permute latency
#pragma unroll
        for (int off = 32; off >= 1; off >>= 1) {
            s00 += __shfl_xor(s00, off, 64);
            s10 += __shfl_xor(s10, off, 64);
            s01 += __shfl_xor(s01, off, 64);
            s11 += __shfl_xor(s11, off, 64);
            s02 += __shfl_xor(s02, off, 64);
            s12 += __shfl_xor(s12, off, 64);
            s03 += __shfl_xor(s03, off, 64);
            s13 += __shfl_xor(s13, off, 64);
        }

        if (lane < 4) {
            float a = s00, b = s10;
            if      (lane == 1) { a = s01; b = s11; }
            else if (lane == 2) { a = s02; b = s12; }
            else if (lane == 3) { a = s03; b = s13; }
            // softmax over 2: overflow-safe (exp->inf => p->0)
            float2 pr;
            pr.x = 1.0f / (1.0f + expf(b - a));
            pr.y = 1.0f / (1.0f + expf(a - b));
            out2[row0 + lane] = pr;   // 4 lanes x 8 B = 32 B contiguous
        }
    }
}

extern "C" void kernel_launch(void* const* d_in, const int* in_sizes, int n_in,
                              void* d_out, int out_size, void* d_ws, size_t ws_size,
                              hipStream_t stream) {
    const float* x  = (const float*)d_in[0];
    const float* tf = (const float*)d_in[1];
    const float* ls = (const float*)d_in[2];
    float* out = (float*)d_out;

    const int nrows = in_sizes[0] / D_DIM;  // 262144

    // 2048 blocks x 256 thr = 8192 waves; 4 rows/iter -> 8 iterations/wave
    prompts_kernel<<<2048, 256, 0, stream>>>(x, tf, ls, out, nrows);
}

// Round 4
// 649.150 us; speedup vs baseline: 1.0499x; 1.0452x over previous
//
#include <hip/hip_runtime.h>

// Prompts: out[row,k] = softmax_k( 100 * dot(x[row,:], tf[k,:]/||tf[k]||) )
// rows = 262144, D = 512, K = 2.
// Traffic floor: read 512 MiB x + write 2 MiB out ~= 82 us @ 6.3 TB/s.
// Round-2 evidence: dur_us dominated by harness poison/restore (2 GiB ws fill
// ~335 us + 512 MiB input restore ~165 us); kernel itself sub-175 us.
// This round: same plan, fixed compile — nontemporal builtins need native
// clang vector types, not HIP_vector_type structs.

#define D_DIM 512

typedef float vfloat4 __attribute__((ext_vector_type(4)));
typedef float vfloat2 __attribute__((ext_vector_type(2)));

__device__ __forceinline__ float dot4(vfloat4 a, vfloat4 b) {
    return a.x * b.x + a.y * b.y + a.z * b.z + a.w * b.w;
}

__device__ __forceinline__ vfloat4 nt_load4(const vfloat4* p) {
    return __builtin_nontemporal_load(p);
}

__global__ __launch_bounds__(256, 4) void prompts_kernel(
    const float* __restrict__ x,
    const float* __restrict__ tf,
    const float* __restrict__ logit_scale,
    float* __restrict__ out,
    int nrows)
{
    const int lane          = threadIdx.x & 63;
    const int wave_in_block = threadIdx.x >> 6;
    const int gwave  = blockIdx.x * (blockDim.x >> 6) + wave_in_block;
    const int nwaves = gridDim.x * (blockDim.x >> 6);

    // ---- Per-wave weight setup (tf is 4 KiB, cache-resident) ----
    const vfloat4* tf4 = (const vfloat4*)tf;
    vfloat4 w0a = tf4[lane];        // tf row 0, floats [4i, 4i+4)
    vfloat4 w0b = tf4[64 + lane];   // tf row 0, floats [256+4i, ...)
    vfloat4 w1a = tf4[128 + lane];  // tf row 1
    vfloat4 w1b = tf4[192 + lane];

    float ss0 = dot4(w0a, w0a) + dot4(w0b, w0b);
    float ss1 = dot4(w1a, w1a) + dot4(w1b, w1b);
#pragma unroll
    for (int off = 32; off >= 1; off >>= 1) {
        ss0 += __shfl_xor(ss0, off, 64);
        ss1 += __shfl_xor(ss1, off, 64);
    }

    const float scale = expf(logit_scale[0]);   // = 100.0
    const float inv0  = scale / sqrtf(ss0);
    const float inv1  = scale / sqrtf(ss1);

    w0a *= inv0; w0b *= inv0;
    w1a *= inv1; w1b *= inv1;

    // ---- Persistent grid-stride, 4 rows (8 KiB) per wave-iteration ----
    const vfloat4* x4   = (const vfloat4*)x;
    vfloat2*       out2 = (vfloat2*)out;

    for (int row0 = gwave * 4; row0 < nrows; row0 += nwaves * 4) {
        const vfloat4* p = x4 + (size_t)row0 * (D_DIM / 4);

        // 8 independent nontemporal 16B loads (x is touched exactly once)
        vfloat4 xa0 = nt_load4(p + lane      ), xb0 = nt_load4(p + lane +  64);
        vfloat4 xa1 = nt_load4(p + lane + 128), xb1 = nt_load4(p + lane + 192);
        vfloat4 xa2 = nt_load4(p + lane + 256), xb2 = nt_load4(p + lane + 320);
        vfloat4 xa3 = nt_load4(p + lane + 384), xb3 = nt_load4(p + lane + 448);

        float s00 = dot4(xa0, w0a) + dot4(xb0, w0b);
        float s10 = dot4(xa0, w1a) + dot4(xb0, w1b);
        float s01 = dot4(xa1, w0a) + dot4(xb1, w0b);
        float s11 = dot4(xa1, w1a) + dot4(xb1, w1b);
        float s02 = dot4(xa2, w0a) + dot4(xb2, w0b);
        float s12 = dot4(xa2, w1a) + dot4(xb2, w1b);
        float s03 = dot4(xa3, w0a) + dot4(xb3, w0b);
        float s13 = dot4(xa3, w1a) + dot4(xb3, w1b);

#pragma unroll
        for (int off = 32; off >= 1; off >>= 1) {
            s00 += __shfl_xor(s00, off, 64);
            s10 += __shfl_xor(s10, off, 64);
            s01 += __shfl_xor(s01, off, 64);
            s11 += __shfl_xor(s11, off, 64);
            s02 += __shfl_xor(s02, off, 64);
            s12 += __shfl_xor(s12, off, 64);
            s03 += __shfl_xor(s03, off, 64);
            s13 += __shfl_xor(s13, off, 64);
        }

        if (lane < 4) {
            float a = s00, b = s10;
            if      (lane == 1) { a = s01; b = s11; }
            else if (lane == 2) { a = s02; b = s12; }
            else if (lane == 3) { a = s03; b = s13; }
            // softmax over 2: overflow-safe (exp->inf => p->0)
            vfloat2 pr;
            pr.x = 1.0f / (1.0f + expf(b - a));
            pr.y = 1.0f / (1.0f + expf(a - b));
            __builtin_nontemporal_store(pr, out2 + row0 + lane);
        }
    }
}

extern "C" void kernel_launch(void* const* d_in, const int* in_sizes, int n_in,
                              void* d_out, int out_size, void* d_ws, size_t ws_size,
                              hipStream_t stream) {
    const float* x  = (const float*)d_in[0];
    const float* tf = (const float*)d_in[1];
    const float* ls = (const float*)d_in[2];
    float* out = (float*)d_out;

    const int nrows = in_sizes[0] / D_DIM;  // 262144

    // 1024 blocks x 256 thr = 4096 waves; 4 blocks/CU co-resident (128 VGPR),
    // one pass, 16 iterations per wave, 64 KiB of loads in flight per CU.
    prompts_kernel<<<1024, 256, 0, stream>>>(x, tf, ls, out, nrows);
}